// Round 8
// baseline (226.498 us; speedup 1.0000x reference)
//
#include <hip/hip_runtime.h>
#include <hip/hip_fp16.h>

// Symmetric pair-weight recurrent net, T=8192, 8 steps of s = tanh(M s + b).
// M symmetric, zero diagonal; stored ONLY as strict upper triangle in fp16,
// row-start 16B-aligned: slot(r,j) = crow(r) + j  (j > r), crow(r) % 8 == 0.
// Each sym pass reads every pair weight ONCE, accumulating both directions:
//   y[r] += w * s[j]   (row side, shfl-reduced, 1 atomic per row per tile)
//   y[j] += w * s[r]   (col side, register acc -> LDS -> 1 atomic per col)

constexpr int T     = 8192;
constexpr int IN    = 2048;
constexpr int OUT   = 1024;
constexpr int NPROP = 8;

constexpr int TILE   = 128;
constexpr int NT     = T / TILE;              // 64
constexpr int NTILES = NT * (NT + 1) / 2;     // 2080

// f32 source triangle index (j > r)
__device__ __forceinline__ unsigned triidx(unsigned r, unsigned j) {
    return r * (unsigned)(T - 1) - ((r * (r - 1u)) >> 1) + j - r - 1u;
}

// fp16 padded-triangle row base (halves), 16B-aligned slots: slot(r,j)=crow(r)+j.
// Max touched slot = crow(8191)+8191 = 33587199 (allocation must cover it).
// Write set {crow(r)+j : j>r} is injective across rows; sub-diagonal slots
// alias other rows' data (read-only + masked in sym, NEVER stored).
__device__ __forceinline__ int crow(int r) {
    int q = r >> 3, rem = r & 7;
    return r * T - 8 * (4 * q * (q - 1) + q * (rem + 1));
}
constexpr size_t W16_ALLOC = 33587200;        // slots; > crow(8191)+8191, %8==0

__host__ __device__ __forceinline__ unsigned rowstart(int b) {
    return (unsigned)(b * NT) - (unsigned)((b * (b - 1)) >> 1);
}

__device__ __forceinline__ void tile_decode(unsigned p, int& bi, int& bj) {
    const float A = (float)(2 * NT + 1);      // 129
    bi = (int)((A - sqrtf(A * A - 8.0f * (float)p)) * 0.5f);
    if (bi < 0) bi = 0;
    while (rowstart(bi + 1) <= p) ++bi;
    while (rowstart(bi) > p) --bi;
    bj = bi + (int)(p - rowstart(bi));
}

__device__ __forceinline__ uint4 pack8(const float* v) {
    uint4 pk;
    ushort* us = (ushort*)&pk;
    #pragma unroll
    for (int d = 0; d < 8; ++d) us[d] = __half_as_ushort(__float2half_rn(v[d]));
    return pk;
}

// ---- one-time f32 triangle -> fp16 padded triangle (vectorized stream) ----
// Thread handles 8 consecutive cols of one row: 8 coalesced f32 loads,
// one aligned uint4 store. 8 sweeps x 16 rows = 128 rows per tile.
__global__ __launch_bounds__(256) void conv_kernel(const float* __restrict__ w,
                                                   __half* __restrict__ w16) {
    int bi, bj; tile_decode(blockIdx.x, bi, bj);
    int i0 = bi * TILE, j0 = bj * TILE;
    int t = threadIdx.x;
    int rsub = t >> 4;            // 0..15
    int c8   = (t & 15) * 8;      // 0,8,..,120

    if (bi != bj) {
        #pragma unroll
        for (int sw = 0; sw < 8; ++sw) {
            int r = i0 + sw * 16 + rsub;
            const float* src = w + triidx((unsigned)r, (unsigned)(j0 + c8));
            float v[8];
            #pragma unroll
            for (int d = 0; d < 8; ++d) v[d] = src[d];
            *(uint4*)(w16 + (crow(r) + j0 + c8)) = pack8(v);
        }
    } else {
        #pragma unroll 2
        for (int sw = 0; sw < 8; ++sw) {
            int r  = i0 + sw * 16 + rsub;
            int jb = j0 + c8;
            if (jb + 7 <= r) continue;          // fully at/below diag: skip
            if (jb > r) {                        // fully above: vector path
                const float* src = w + triidx((unsigned)r, (unsigned)jb);
                float v[8];
                #pragma unroll
                for (int d = 0; d < 8; ++d) v[d] = src[d];
                *(uint4*)(w16 + (crow(r) + jb)) = pack8(v);
            } else {                             // straddles diag: elementwise
                #pragma unroll
                for (int d = 0; d < 8; ++d) {
                    int j = jb + d;
                    if (j > r)
                        w16[crow(r) + j] =
                            __float2half_rn(w[triidx((unsigned)r, (unsigned)j)]);
                }
            }
        }
    }
}

__global__ __launch_bounds__(256) void init_kernel(const float* __restrict__ in,
                                                   float* __restrict__ s,
                                                   float* __restrict__ y) {
    int n = blockIdx.x * 256 + threadIdx.x;
    if (n < T) { s[n] = (n < IN) ? in[n] : 0.0f; y[n] = 0.0f; }
}

// ---- fused symmetric tile pass: mode 0=full, 1=iter1 (bi<16 grid), 2=iter8 ----
__global__ __launch_bounds__(256) void sym_kernel(const __half* __restrict__ w16,
                                                  const float* __restrict__ s,
                                                  float* __restrict__ y, int mode) {
    __shared__ float sIl[TILE], sJl[TILE];
    __shared__ float colpart[4][TILE];

    int bi, bj; tile_decode(blockIdx.x, bi, bj);
    if (mode == 2 && bj < (T - OUT) / TILE) return;    // iter8: only y[7168..]
    bool doRow = (mode == 1) ? (bj < IN / TILE) : true; // iter1: s[j]==0 bj>=16

    int i0 = bi * TILE, j0 = bj * TILE;
    int t = threadIdx.x;
    if (t < TILE) sIl[t] = s[i0 + t];
    else          sJl[t - TILE] = s[j0 + (t - TILE)];
    __syncthreads();

    int l = t & 63, wv = t >> 6;
    int g = l & 15, ro = l >> 4;
    int cbase = j0 + g * 8;

    float sjv[8];
    #pragma unroll
    for (int d = 0; d < 8; ++d) sjv[d] = sJl[g * 8 + d];
    float colacc[8] = {0.f, 0.f, 0.f, 0.f, 0.f, 0.f, 0.f, 0.f};
    float rps[8];

    if (bi != bj) {
        // ---- off-diagonal: branch-free, all 8 weights valid ----
        #pragma unroll
        for (int k = 0; k < 8; ++k) {
            int rr = wv * 32 + k * 4 + ro;
            int r  = i0 + rr;
            uint4 wq = *(const uint4*)(w16 + (crow(r) + cbase));
            const __half2* h2 = (const __half2*)&wq;
            float2 f0 = __half22float2(h2[0]);
            float2 f1 = __half22float2(h2[1]);
            float2 f2 = __half22float2(h2[2]);
            float2 f3 = __half22float2(h2[3]);
            float wf[8] = {f0.x, f0.y, f1.x, f1.y, f2.x, f2.y, f3.x, f3.y};
            float si = sIl[rr];
            float rp = 0.0f;
            #pragma unroll
            for (int d = 0; d < 8; ++d) {
                colacc[d] = fmaf(wf[d], si, colacc[d]);
                rp        = fmaf(wf[d], sjv[d], rp);
            }
            rps[k] = rp;
        }
    } else {
        // ---- diagonal: mask sub/on-diagonal slots (alias other rows) ----
        #pragma unroll
        for (int k = 0; k < 8; ++k) {
            int rr = wv * 32 + k * 4 + ro;
            int r  = i0 + rr;
            uint4 wq = *(const uint4*)(w16 + (crow(r) + cbase));
            const __half2* h2 = (const __half2*)&wq;
            float2 f0 = __half22float2(h2[0]);
            float2 f1 = __half22float2(h2[1]);
            float2 f2 = __half22float2(h2[2]);
            float2 f3 = __half22float2(h2[3]);
            float wf[8] = {f0.x, f0.y, f1.x, f1.y, f2.x, f2.y, f3.x, f3.y};
            float si = sIl[rr];
            float rp = 0.0f;
            #pragma unroll
            for (int d = 0; d < 8; ++d) {
                float we = (cbase + d > r) ? wf[d] : 0.0f;
                colacc[d] = fmaf(we, si, colacc[d]);
                rp        = fmaf(we, sjv[d], rp);
            }
            rps[k] = rp;
        }
    }

    if (doRow) {
        #pragma unroll
        for (int k = 0; k < 8; ++k) {
            float rp = rps[k];
            rp += __shfl_xor(rp, 1, 64);
            rp += __shfl_xor(rp, 2, 64);
            rp += __shfl_xor(rp, 4, 64);
            rp += __shfl_xor(rp, 8, 64);
            if (g == 0) atomicAdd(&y[i0 + wv * 32 + k * 4 + ro], rp);
        }
    }

    #pragma unroll
    for (int d = 0; d < 8; ++d) {
        colacc[d] += __shfl_xor(colacc[d], 16, 64);
        colacc[d] += __shfl_xor(colacc[d], 32, 64);
    }
    if (l < 16) {
        #pragma unroll
        for (int d = 0; d < 8; ++d) colpart[wv][g * 8 + d] = colacc[d];
    }
    __syncthreads();
    if (t < TILE) {
        float c = colpart[0][t] + colpart[1][t] + colpart[2][t] + colpart[3][t];
        atomicAdd(&y[j0 + t], c);
    }
}

__global__ __launch_bounds__(256) void act_kernel(const float* __restrict__ b,
                                                  float* __restrict__ s,
                                                  float* __restrict__ y) {
    int n = blockIdx.x * 256 + threadIdx.x;
    if (n < T) { s[n] = tanhf(y[n] + b[n]); y[n] = 0.0f; }
}

__global__ __launch_bounds__(256) void actout_kernel(const float* __restrict__ b,
                                                     const float* __restrict__ y,
                                                     float* __restrict__ o) {
    int n = blockIdx.x * 256 + threadIdx.x;
    if (n < OUT) o[n] = tanhf(y[T - OUT + n] + b[T - OUT + n]);
}

extern "C" void kernel_launch(void* const* d_in, const int* in_sizes, int n_in,
                              void* d_out, int out_size, void* d_ws, size_t ws_size,
                              hipStream_t stream) {
    const float* in = (const float*)d_in[0];   // inputs [2048]
    const float* w  = (const float*)d_in[1];   // w_flat [T*(T-1)/2] f32
    const float* b  = (const float*)d_in[2];   // b [8192] f32
    float* out = (float*)d_out;                // [1024] f32

    __half* w16 = (__half*)d_ws;                               // 67.17 MB + pad
    float*  s   = (float*)((char*)d_ws + W16_ALLOC * sizeof(__half));
    float*  y   = s + T;

    conv_kernel<<<NTILES, 256, 0, stream>>>(w, w16);
    init_kernel<<<T / 256, 256, 0, stream>>>(in, s, y);

    // iter 1: only tiles with bi<16 touch nonzero state (contiguous p < 904)
    sym_kernel<<<rowstart(IN / TILE), 256, 0, stream>>>(w16, s, y, 1);
    act_kernel<<<T / 256, 256, 0, stream>>>(b, s, y);
    // iters 2..7
    for (int it = 1; it < NPROP - 1; ++it) {
        sym_kernel<<<NTILES, 256, 0, stream>>>(w16, s, y, 0);
        act_kernel<<<T / 256, 256, 0, stream>>>(b, s, y);
    }
    // iter 8: only outputs 7168.. needed
    sym_kernel<<<NTILES, 256, 0, stream>>>(w16, s, y, 2);
    actout_kernel<<<OUT / 256, 256, 0, stream>>>(b, y, out);
}

// Round 9
// 183.519 us; speedup vs baseline: 1.2342x; 1.2342x over previous
//
#include <hip/hip_runtime.h>
#include <hip/hip_fp16.h>

// Symmetric pair-weight recurrent net, T=8192, 8 steps of s = tanh(M s + b).
// M symmetric, zero diagonal; stored ONLY as strict upper triangle in fp16,
// row-start 16B-aligned: slot(r,j) = crow(r) + j  (j > r), crow(r) % 8 == 0.
// Each sym pass reads every pair weight ONCE, accumulating both directions:
//   y[r] += w * s[j]   (row side, shfl-reduced, 1 atomic per row per tile)
//   y[j] += w * s[r]   (col side, register acc -> LDS -> 1 atomic per col)

constexpr int T     = 8192;
constexpr int IN    = 2048;
constexpr int OUT   = 1024;
constexpr int NPROP = 8;

constexpr int TILE   = 128;
constexpr int NT     = T / TILE;              // 64
constexpr int NTILES = NT * (NT + 1) / 2;     // 2080

// f32 source triangle index (j > r)
__device__ __forceinline__ unsigned triidx(unsigned r, unsigned j) {
    return r * (unsigned)(T - 1) - ((r * (r - 1u)) >> 1) + j - r - 1u;
}

// fp16 padded-triangle row base (halves), 16B-aligned slots: slot(r,j)=crow(r)+j.
// Max touched slot = crow(8191)+8191 = 33587199 (allocation must cover it).
// Write set {crow(r)+j : j>r} is injective across rows; sub-diagonal slots
// alias other rows' data (read-only + masked in sym, NEVER stored).
__device__ __forceinline__ int crow(int r) {
    int q = r >> 3, rem = r & 7;
    return r * T - 8 * (4 * q * (q - 1) + q * (rem + 1));
}
constexpr size_t W16_ALLOC = 33587200;        // slots; > crow(8191)+8191, %8==0

__host__ __device__ __forceinline__ unsigned rowstart(int b) {
    return (unsigned)(b * NT) - (unsigned)((b * (b - 1)) >> 1);
}

__device__ __forceinline__ void tile_decode(unsigned p, int& bi, int& bj) {
    const float A = (float)(2 * NT + 1);      // 129
    bi = (int)((A - sqrtf(A * A - 8.0f * (float)p)) * 0.5f);
    if (bi < 0) bi = 0;
    while (rowstart(bi + 1) <= p) ++bi;
    while (rowstart(bi) > p) --bi;
    bj = bi + (int)(p - rowstart(bi));
}

__device__ __forceinline__ uint4 pack8(const float* v) {
    uint4 pk;
    ushort* us = (ushort*)&pk;
    #pragma unroll
    for (int d = 0; d < 8; ++d) us[d] = __half_as_ushort(__float2half_rn(v[d]));
    return pk;
}

// ---- one-time f32 triangle -> fp16 padded triangle ----
// No inner loop: one block = one 16-row sweep of one tile; each thread does
// 8 independent coalesced f32 loads + 1 aligned uint4 store, then exits.
// Grid = NTILES * 8 keeps wave slots refilled -> BW-bound, not latency-bound.
__global__ __launch_bounds__(256) void conv_kernel(const float* __restrict__ w,
                                                   __half* __restrict__ w16) {
    unsigned bid = blockIdx.x;
    int sweep = (int)(bid & 7u);
    int bi, bj; tile_decode(bid >> 3, bi, bj);
    int i0 = bi * TILE, j0 = bj * TILE;
    int t = threadIdx.x;
    int r  = i0 + sweep * 16 + (t >> 4);
    int jb = j0 + (t & 15) * 8;

    if (bi != bj || jb > r) {
        const float* src = w + triidx((unsigned)r, (unsigned)jb);
        float v[8];
        #pragma unroll
        for (int d = 0; d < 8; ++d) v[d] = src[d];
        *(uint4*)(w16 + (crow(r) + jb)) = pack8(v);
    } else if (jb + 7 > r) {                   // straddles diagonal
        #pragma unroll
        for (int d = 0; d < 8; ++d) {
            int j = jb + d;
            if (j > r)
                w16[crow(r) + j] =
                    __float2half_rn(w[triidx((unsigned)r, (unsigned)j)]);
        }
    }                                          // fully at/below diag: skip
}

__global__ __launch_bounds__(256) void init_kernel(const float* __restrict__ in,
                                                   float* __restrict__ s,
                                                   float* __restrict__ y) {
    int n = blockIdx.x * 256 + threadIdx.x;
    if (n < T) { s[n] = (n < IN) ? in[n] : 0.0f; y[n] = 0.0f; }
}

// ---- fused symmetric tile pass (R7 body): mode 0=full, 1=iter1, 2=iter8 ----
__global__ __launch_bounds__(256) void sym_kernel(const __half* __restrict__ w16,
                                                  const float* __restrict__ s,
                                                  float* __restrict__ y, int mode) {
    __shared__ float sIl[TILE], sJl[TILE];
    __shared__ float colpart[4][TILE];

    int bi, bj; tile_decode(blockIdx.x, bi, bj);
    if (mode == 2 && bj < (T - OUT) / TILE) return;    // iter8: only y[7168..]
    bool doRow = (mode == 1) ? (bj < IN / TILE) : true; // iter1: s[j]==0 bj>=16

    int i0 = bi * TILE, j0 = bj * TILE;
    int t = threadIdx.x;
    if (t < TILE) sIl[t] = s[i0 + t];
    else          sJl[t - TILE] = s[j0 + (t - TILE)];
    __syncthreads();

    int l = t & 63, wv = t >> 6;
    int g = l & 15, ro = l >> 4;
    int cbase = j0 + g * 8;

    float sjv[8];
    #pragma unroll
    for (int d = 0; d < 8; ++d) sjv[d] = sJl[g * 8 + d];
    float colacc[8] = {0.f, 0.f, 0.f, 0.f, 0.f, 0.f, 0.f, 0.f};

    #pragma unroll
    for (int k = 0; k < 8; ++k) {
        int rr = wv * 32 + k * 4 + ro;
        int r  = i0 + rr;
        // aligned uint4: crow(r)%8==0, cbase%8==0. Sub-diagonal slots in diag
        // tiles read in-allocation garbage and are masked below.
        uint4 wq = *(const uint4*)(w16 + (crow(r) + cbase));
        const __half2* h2 = (const __half2*)&wq;
        float2 f0 = __half22float2(h2[0]);
        float2 f1 = __half22float2(h2[1]);
        float2 f2 = __half22float2(h2[2]);
        float2 f3 = __half22float2(h2[3]);
        float wf[8] = {f0.x, f0.y, f1.x, f1.y, f2.x, f2.y, f3.x, f3.y};

        float si = sIl[rr];
        float rp = 0.0f;
        #pragma unroll
        for (int d = 0; d < 8; ++d) {
            float we = (cbase + d > r) ? wf[d] : 0.0f;   // strict upper only
            colacc[d] = fmaf(we, si, colacc[d]);
            rp        = fmaf(we, sjv[d], rp);
        }
        if (doRow) {
            rp += __shfl_xor(rp, 1, 64);
            rp += __shfl_xor(rp, 2, 64);
            rp += __shfl_xor(rp, 4, 64);
            rp += __shfl_xor(rp, 8, 64);
            if (g == 0) atomicAdd(&y[r], rp);
        }
    }

    #pragma unroll
    for (int d = 0; d < 8; ++d) {
        colacc[d] += __shfl_xor(colacc[d], 16, 64);
        colacc[d] += __shfl_xor(colacc[d], 32, 64);
    }
    if (l < 16) {
        #pragma unroll
        for (int d = 0; d < 8; ++d) colpart[wv][g * 8 + d] = colacc[d];
    }
    __syncthreads();
    if (t < TILE) {
        float c = colpart[0][t] + colpart[1][t] + colpart[2][t] + colpart[3][t];
        atomicAdd(&y[j0 + t], c);
    }
}

__global__ __launch_bounds__(256) void act_kernel(const float* __restrict__ b,
                                                  float* __restrict__ s,
                                                  float* __restrict__ y) {
    int n = blockIdx.x * 256 + threadIdx.x;
    if (n < T) { s[n] = tanhf(y[n] + b[n]); y[n] = 0.0f; }
}

__global__ __launch_bounds__(256) void actout_kernel(const float* __restrict__ b,
                                                     const float* __restrict__ y,
                                                     float* __restrict__ o) {
    int n = blockIdx.x * 256 + threadIdx.x;
    if (n < OUT) o[n] = tanhf(y[T - OUT + n] + b[T - OUT + n]);
}

extern "C" void kernel_launch(void* const* d_in, const int* in_sizes, int n_in,
                              void* d_out, int out_size, void* d_ws, size_t ws_size,
                              hipStream_t stream) {
    const float* in = (const float*)d_in[0];   // inputs [2048]
    const float* w  = (const float*)d_in[1];   // w_flat [T*(T-1)/2] f32
    const float* b  = (const float*)d_in[2];   // b [8192] f32
    float* out = (float*)d_out;                // [1024] f32

    __half* w16 = (__half*)d_ws;                               // 67.17 MB + pad
    float*  s   = (float*)((char*)d_ws + W16_ALLOC * sizeof(__half));
    float*  y   = s + T;

    conv_kernel<<<NTILES * 8, 256, 0, stream>>>(w, w16);
    init_kernel<<<T / 256, 256, 0, stream>>>(in, s, y);

    // iter 1: only tiles with bi<16 touch nonzero state (contiguous p < 904)
    sym_kernel<<<rowstart(IN / TILE), 256, 0, stream>>>(w16, s, y, 1);
    act_kernel<<<T / 256, 256, 0, stream>>>(b, s, y);
    // iters 2..7
    for (int it = 1; it < NPROP - 1; ++it) {
        sym_kernel<<<NTILES, 256, 0, stream>>>(w16, s, y, 0);
        act_kernel<<<T / 256, 256, 0, stream>>>(b, s, y);
    }
    // iter 8: only outputs 7168.. needed
    sym_kernel<<<NTILES, 256, 0, stream>>>(w16, s, y, 2);
    actout_kernel<<<OUT / 256, 256, 0, stream>>>(b, y, out);
}